// Round 2
// baseline (222.487 us; speedup 1.0000x reference)
//
#include <hip/hip_runtime.h>

#define NB 32
#define NL 6
#define NR 8
#define NH 64
#define NTRAJ 262144        // 8^6
#define F4_PER_B (NTRAJ * NL / 4)     // 393216 float4 per batch element
#define BLOCKS_PER_B 64               // 64 x 32 = 2048 blocks = 8 blocks/CU x 256 CUs
#define F4_PER_BLOCK (F4_PER_B / BLOCKS_PER_B)   // 6144 float4 = 96 KiB per block
#define SCATTER_ITERS (F4_PER_BLOCK / 256)       // 24
// out shape: (NB, NTRAJ, NL) fp32, flat idx = b*NTRAJ*NL + n*NL + l

// native clang vector type: __builtin_nontemporal_store rejects HIP_vector_type
typedef float vfloat4 __attribute__((ext_vector_type(4)));

// Kernel 1: q0[b][l][r] = W3[0] . relu(W2 @ relu(W1 @ [rp[l,r,0], phi[b,l]] + b1) + b2) + b3[0]
// One block (1 wave, 64 threads) per (b,l,r). 1536 blocks. ~microseconds.
__global__ __launch_bounds__(64) void q0_kernel(
    const float* __restrict__ phi,   // (B, L)
    const float* __restrict__ rp,    // (L, R, 1)
    const float* __restrict__ W1,    // (H, 2)
    const float* __restrict__ b1,    // (H)
    const float* __restrict__ W2,    // (H, H)
    const float* __restrict__ b2,    // (H)
    const float* __restrict__ W3,    // (6, H) -> row 0
    const float* __restrict__ b3,    // (6)
    float* __restrict__ q0)          // (B, L, R) flat
{
    const int bid = blockIdx.x;      // = (b*NL + l)*NR + r
    const int r  = bid & 7;
    const int bl = bid >> 3;         // b*NL + l
    const int l  = bl % NL;
    const int h  = threadIdx.x;      // 0..63

    const float x = rp[l * NR + r];  // Z==1
    const float p = phi[bl];

    float h1 = fmaf(W1[h * 2 + 0], x, fmaf(W1[h * 2 + 1], p, b1[h]));
    h1 = fmaxf(h1, 0.0f);

    __shared__ float s_h1[NH];
    s_h1[h] = h1;
    __syncthreads();

    float acc = b2[h];
    const float* w2row = W2 + h * NH;
    #pragma unroll
    for (int k = 0; k < NH; ++k) acc = fmaf(w2row[k], s_h1[k], acc);
    const float h2 = fmaxf(acc, 0.0f);

    float v = W3[h] * h2;
    // wave-64 shuffle reduction
    #pragma unroll
    for (int off = 32; off > 0; off >>= 1)
        v += __shfl_down(v, off, 64);

    if (h == 0) q0[bid] = v + b3[0];
}

// Kernel 2: out[b][n][l] = q0[b][l][(n >> 3l) & 7].
// Persistent-style: 2048 blocks (full residency, 8/CU), each streams a
// CONTIGUOUS 96 KiB chunk of one batch element via a 24-iter loop of
// coalesced float4 stores (lane i -> base+16i, full-line bursts).
// This amortizes the q0-load/barrier block preamble that previously ran
// 49152 times (one 4 KiB store per tiny block -> block-turnover-limited,
// ~2.4 TB/s). Every 3 float4 = 12 floats = trajectories {n=2k, 2k+1}.
// Within one block, k spans exactly [x*2048, (x+1)*2048), so digits 4 and 5
// (k>>11, k>>14) are block-uniform -> hoisted out of the loop.
__global__ __launch_bounds__(256, 8) void scatter_kernel(
    const float* __restrict__ q0,    // (B, L, R)
    float* __restrict__ out)         // (B, NTRAJ, L) flat floats
{
    __shared__ float s[NL * NR];     // 48 floats for this block's b
    const int b   = blockIdx.y;
    const int x   = blockIdx.x;
    const int tid = threadIdx.x;

    if (tid < NL * NR) s[tid] = q0[b * NL * NR + tid];
    __syncthreads();

    // block-uniform digits: k>>11 == x for every k in this block
    const float v4 = s[32 + (x        & 7)];
    const float v5 = s[40 + ((x >> 3) & 7)];

    vfloat4* __restrict__ outb = (vfloat4*)out
        + (size_t)b * F4_PER_B + (size_t)x * F4_PER_BLOCK;
    const unsigned ubase = (unsigned)x * F4_PER_BLOCK + tid;

    #pragma unroll 4
    for (int it = 0; it < SCATTER_ITERS; ++it) {
        const unsigned u = ubase + it * 256u;         // float4 index within b
        const unsigned k = u / 3u;                    // pair index -> n = 2k (magic-mul)
        const unsigned m = u - 3u * k;                // position in the 12-float group

        // digits of n = 2k:  d0 = (2k)&7 (even), d_l = (k >> (3l-1)) & 7 for l>=1
        const float2 v0 = ((const float2*)s)[k & 3u];        // s[d0], s[d0+1]
        const float  v1 = s[ 8 + ((k >> 2) & 7u)];
        const float  v2 = s[16 + ((k >> 5) & 7u)];
        const float  v3 = s[24 + ((k >> 8) & 7u)];

        // group layout: [v0a v1 v2 v3 | v4 v5 v0b v1 | v2 v3 v4 v5]
        vfloat4 val;
        val.x = (m == 0) ? v0.x : ((m == 1) ? v4   : v2);
        val.y = (m == 0) ? v1   : ((m == 1) ? v5   : v3);
        val.z = (m == 0) ? v2   : ((m == 1) ? v0.y : v4);
        val.w = (m == 0) ? v3   : ((m == 1) ? v1   : v5);

        __builtin_nontemporal_store(val, &outb[it * 256 + tid]);
    }
}

extern "C" void kernel_launch(void* const* d_in, const int* in_sizes, int n_in,
                              void* d_out, int out_size, void* d_ws, size_t ws_size,
                              hipStream_t stream) {
    const float* phi = (const float*)d_in[0];  // (32, 6)
    const float* rp  = (const float*)d_in[1];  // (6, 8, 1)
    const float* W1  = (const float*)d_in[2];  // (64, 2)
    const float* b1  = (const float*)d_in[3];  // (64,)
    const float* W2  = (const float*)d_in[4];  // (64, 64)
    const float* b2  = (const float*)d_in[5];  // (64,)
    const float* W3  = (const float*)d_in[6];  // (6, 64)
    const float* b3  = (const float*)d_in[7];  // (6,)
    float* out = (float*)d_out;
    float* q0  = (float*)d_ws;                 // 1536 floats = 6 KB

    q0_kernel<<<NB * NL * NR, 64, 0, stream>>>(phi, rp, W1, b1, W2, b2, W3, b3, q0);

    dim3 grid(BLOCKS_PER_B, NB);
    scatter_kernel<<<grid, 256, 0, stream>>>(q0, out);
}

// Round 3
// 213.625 us; speedup vs baseline: 1.0415x; 1.0415x over previous
//
#include <hip/hip_runtime.h>

#define NB 32
#define NL 6
#define NR 8
#define NH 64
#define NTRAJ 262144        // 8^6
#define F4_PER_B (NTRAJ * NL / 4)     // 393216 float4 per batch element
#define BLOCKS_PER_B 64               // 64 x 32 = 2048 blocks
#define F4_PER_BLOCK (F4_PER_B / BLOCKS_PER_B)   // 6144 float4 = 96 KiB per block
#define SCATTER_ITERS (F4_PER_BLOCK / 256)       // 24
#define HALF_ITERS (SCATTER_ITERS / 2)           // 12
// out shape: (NB, NTRAJ, NL) fp32, flat idx = b*NTRAJ*NL + n*NL + l

// native clang vector type (plays well with builtins / register arrays)
typedef float vfloat4 __attribute__((ext_vector_type(4)));

// Kernel 1: q0[b][l][r] = W3[0] . relu(W2 @ relu(W1 @ [rp[l,r,0], phi[b,l]] + b1) + b2) + b3[0]
// One block (1 wave, 64 threads) per (b,l,r). 1536 blocks. ~microseconds.
__global__ __launch_bounds__(64) void q0_kernel(
    const float* __restrict__ phi,   // (B, L)
    const float* __restrict__ rp,    // (L, R, 1)
    const float* __restrict__ W1,    // (H, 2)
    const float* __restrict__ b1,    // (H)
    const float* __restrict__ W2,    // (H, H)
    const float* __restrict__ b2,    // (H)
    const float* __restrict__ W3,    // (6, H) -> row 0
    const float* __restrict__ b3,    // (6)
    float* __restrict__ q0)          // (B, L, R) flat
{
    const int bid = blockIdx.x;      // = (b*NL + l)*NR + r
    const int r  = bid & 7;
    const int bl = bid >> 3;         // b*NL + l
    const int l  = bl % NL;
    const int h  = threadIdx.x;      // 0..63

    const float x = rp[l * NR + r];  // Z==1
    const float p = phi[bl];

    float h1 = fmaf(W1[h * 2 + 0], x, fmaf(W1[h * 2 + 1], p, b1[h]));
    h1 = fmaxf(h1, 0.0f);

    __shared__ float s_h1[NH];
    s_h1[h] = h1;
    __syncthreads();

    float acc = b2[h];
    const float* w2row = W2 + h * NH;
    #pragma unroll
    for (int k = 0; k < NH; ++k) acc = fmaf(w2row[k], s_h1[k], acc);
    const float h2 = fmaxf(acc, 0.0f);

    float v = W3[h] * h2;
    // wave-64 shuffle reduction
    #pragma unroll
    for (int off = 32; off > 0; off >>= 1)
        v += __shfl_down(v, off, 64);

    if (h == 0) q0[bid] = v + b3[0];
}

// Kernel 2: out[b][n][l] = q0[b][l][(n >> 3l) & 7].
// Phase-split: per half-chunk, (a) gather 12 float4 into REGISTERS (all LDS
// reads issue up front, latencies overlap), then (b) a dependency-free burst
// of 12 coalesced float4 stores — fill-shaped, no LDS/wait between stores.
// Three prior formulations with per-store LDS gather all capped at ~2.4 TB/s
// while fillBuffer hits 6.7 TB/s on the same buffer; this isolates (and, if
// the theory holds, removes) the ds_read->store dependency gating.
// Every 3 float4 = 12 floats = trajectories {n=2k, 2k+1}. Within one block,
// k spans [x*2048,(x+1)*2048) so digits 4,5 (k>>11, k>>14) are block-uniform.
__global__ __launch_bounds__(256) void scatter_kernel(
    const float* __restrict__ q0,    // (B, L, R)
    float* __restrict__ out)         // (B, NTRAJ, L) flat floats
{
    __shared__ float s[NL * NR];     // 48 floats for this block's b
    const int b   = blockIdx.y;
    const int x   = blockIdx.x;
    const int tid = threadIdx.x;

    if (tid < NL * NR) s[tid] = q0[b * NL * NR + tid];
    __syncthreads();

    // block-uniform digits: k>>11 == x for every k in this block
    const float v4 = s[32 + (x        & 7)];
    const float v5 = s[40 + ((x >> 3) & 7)];

    vfloat4* __restrict__ outb = (vfloat4*)out
        + (size_t)b * F4_PER_B + (size_t)x * F4_PER_BLOCK;
    const unsigned ubase = (unsigned)x * F4_PER_BLOCK + tid;

    #pragma unroll 1
    for (int half = 0; half < 2; ++half) {
        vfloat4 vals[HALF_ITERS];    // 48 VGPR, statically indexed (full unroll)

        #pragma unroll
        for (int j = 0; j < HALF_ITERS; ++j) {
            const unsigned u = ubase + (unsigned)(half * HALF_ITERS + j) * 256u;
            const unsigned k = u / 3u;                    // pair index -> n = 2k
            const unsigned m = u - 3u * k;                // position in 12-float group

            // digits of n = 2k: d0 = (2k)&7 (even), d_l = (k >> (3l-1)) & 7
            const float2 v0 = ((const float2*)s)[k & 3u];        // s[d0], s[d0+1]
            const float  v1 = s[ 8 + ((k >> 2) & 7u)];
            const float  v2 = s[16 + ((k >> 5) & 7u)];
            const float  v3 = s[24 + ((k >> 8) & 7u)];

            // group layout: [v0a v1 v2 v3 | v4 v5 v0b v1 | v2 v3 v4 v5]
            vfloat4 val;
            val.x = (m == 0) ? v0.x : ((m == 1) ? v4   : v2);
            val.y = (m == 0) ? v1   : ((m == 1) ? v5   : v3);
            val.z = (m == 0) ? v2   : ((m == 1) ? v0.y : v4);
            val.w = (m == 0) ? v3   : ((m == 1) ? v1   : v5);
            vals[j] = val;
        }

        // dependency-free store burst: data already in registers
        vfloat4* __restrict__ o = outb + half * (HALF_ITERS * 256) + tid;
        #pragma unroll
        for (int j = 0; j < HALF_ITERS; ++j)
            o[j * 256] = vals[j];
    }
}

extern "C" void kernel_launch(void* const* d_in, const int* in_sizes, int n_in,
                              void* d_out, int out_size, void* d_ws, size_t ws_size,
                              hipStream_t stream) {
    const float* phi = (const float*)d_in[0];  // (32, 6)
    const float* rp  = (const float*)d_in[1];  // (6, 8, 1)
    const float* W1  = (const float*)d_in[2];  // (64, 2)
    const float* b1  = (const float*)d_in[3];  // (64,)
    const float* W2  = (const float*)d_in[4];  // (64, 64)
    const float* b2  = (const float*)d_in[5];  // (64,)
    const float* W3  = (const float*)d_in[6];  // (6, 64)
    const float* b3  = (const float*)d_in[7];  // (6,)
    float* out = (float*)d_out;
    float* q0  = (float*)d_ws;                 // 1536 floats = 6 KB

    q0_kernel<<<NB * NL * NR, 64, 0, stream>>>(phi, rp, W1, b1, W2, b2, W3, b3, q0);

    dim3 grid(BLOCKS_PER_B, NB);
    scatter_kernel<<<grid, 256, 0, stream>>>(q0, out);
}

// Round 4
// 213.518 us; speedup vs baseline: 1.0420x; 1.0005x over previous
//
#include <hip/hip_runtime.h>

#define NB 32
#define NL 6
#define NR 8
#define NH 64
#define NTRAJ 262144        // 8^6
#define F4_PER_B (NTRAJ * NL / 4)     // 393216 float4 per batch element
#define BLOCKS_PER_B 64               // 64 x 32 = 2048 blocks
#define F4_PER_BLOCK (F4_PER_B / BLOCKS_PER_B)   // 6144 float4 = 96 KiB per block
#define PAT_F4 768                    // one d3-sub-chunk = 256 groups = 768 float4 = 12 KiB
// out shape: (NB, NTRAJ, NL) fp32, flat idx = b*NTRAJ*NL + n*NL + l

// native clang vector type (register arrays / clean codegen)
typedef float vfloat4 __attribute__((ext_vector_type(4)));

// Kernel 1: q0[b][l][r] = W3[0] . relu(W2 @ relu(W1 @ [rp[l,r,0], phi[b,l]] + b1) + b2) + b3[0]
// One block (1 wave, 64 threads) per (b,l,r). 1536 blocks. ~microseconds.
__global__ __launch_bounds__(64) void q0_kernel(
    const float* __restrict__ phi,   // (B, L)
    const float* __restrict__ rp,    // (L, R, 1)
    const float* __restrict__ W1,    // (H, 2)
    const float* __restrict__ b1,    // (H)
    const float* __restrict__ W2,    // (H, H)
    const float* __restrict__ b2,    // (H)
    const float* __restrict__ W3,    // (6, H) -> row 0
    const float* __restrict__ b3,    // (6)
    float* __restrict__ q0)          // (B, L, R) flat
{
    const int bid = blockIdx.x;      // = (b*NL + l)*NR + r
    const int r  = bid & 7;
    const int bl = bid >> 3;         // b*NL + l
    const int l  = bl % NL;
    const int h  = threadIdx.x;      // 0..63

    const float x = rp[l * NR + r];  // Z==1
    const float p = phi[bl];

    float h1 = fmaf(W1[h * 2 + 0], x, fmaf(W1[h * 2 + 1], p, b1[h]));
    h1 = fmaxf(h1, 0.0f);

    __shared__ float s_h1[NH];
    s_h1[h] = h1;
    __syncthreads();

    float acc = b2[h];
    const float* w2row = W2 + h * NH;
    #pragma unroll
    for (int k = 0; k < NH; ++k) acc = fmaf(w2row[k], s_h1[k], acc);
    const float h2 = fmaxf(acc, 0.0f);

    float v = W3[h] * h2;
    // wave-64 shuffle reduction
    #pragma unroll
    for (int off = 32; off > 0; off >>= 1)
        v += __shfl_down(v, off, 64);

    if (h == 0) q0[bid] = v + b3[0];
}

// Kernel 2: out[b][n][l] = q0[b][l][(n >> 3l) & 7].
// Block chunk = 2048 groups (k in [x*2048,(x+1)*2048)); digits d4,d5 block-
// uniform; digit d3 = sub-chunk index c (256 groups each). Sub-chunks differ
// ONLY in v3, at group positions 3 and 9 = .w of m==0 quads / .y of m==2
// quads. So: precompute the 12 KiB sub-chunk pattern ONCE in LDS (3 gather
// iters), then stream it 8x with per-store cost of 1 conflict-free
// ds_read_b128 + 2 cndmask + 1 store. Previous versions spent ~30 VALU +
// 4 gather-ds_reads per store (32 waves/CU x 24 iters ~ 60k cyc, right at the
// 72k-cyc HBM budget) -> issue-rate co-limited at ~2.3 TB/s. This cuts the
// per-store front-end ~8x; stores become the only significant pipe.
__global__ __launch_bounds__(256) void scatter_kernel(
    const float* __restrict__ q0,    // (B, L, R)
    float* __restrict__ out)         // (B, NTRAJ, L) flat floats
{
    __shared__ float   s_tab[NL * NR];   // 48 floats for this block's b
    __shared__ vfloat4 pat4[PAT_F4];     // 12 KiB sub-chunk pattern
    const int b   = blockIdx.y;
    const int x   = blockIdx.x;
    const int tid = threadIdx.x;

    if (tid < NL * NR) s_tab[tid] = q0[b * NL * NR + tid];
    __syncthreads();

    // block-uniform digits d4,d5: k>>11 == x
    const float v4 = s_tab[32 + (x        & 7)];
    const float v5 = s_tab[40 + ((x >> 3) & 7)];

    // ---- phase 1: build the d3=0 sub-chunk pattern (v3 slots get baked with
    // s_tab[24]; they are unconditionally replaced during streaming) ----
    #pragma unroll
    for (int j = 0; j < 3; ++j) {
        const unsigned pf = (unsigned)j * 256u + tid;             // [0, 768)
        const unsigned u  = (unsigned)x * F4_PER_BLOCK + pf;      // global f4 idx in b
        const unsigned k  = u / 3u;                               // pair index (magic-mul)
        const unsigned m  = u - 3u * k;                           // quad position in group

        // digits of n = 2k: d0=(2k)&7 (even), d_l = (k >> (3l-1)) & 7
        const float2 v0 = ((const float2*)s_tab)[k & 3u];         // s[d0], s[d0+1]
        const float  v1 = s_tab[ 8 + ((k >> 2) & 7u)];
        const float  v2 = s_tab[16 + ((k >> 5) & 7u)];
        const float  v3 = s_tab[24];                              // placeholder (d3=0)

        // group layout: [v0a v1 v2 v3 | v4 v5 v0b v1 | v2 v3 v4 v5]
        vfloat4 val;
        val.x = (m == 0) ? v0.x : ((m == 1) ? v4   : v2);
        val.y = (m == 0) ? v1   : ((m == 1) ? v5   : v3);
        val.z = (m == 0) ? v2   : ((m == 1) ? v0.y : v4);
        val.w = (m == 0) ? v3   : ((m == 1) ? v1   : v5);
        pat4[pf] = val;
    }
    __syncthreads();

    // ---- phase 2: stream the pattern 8x, substituting v3 per sub-chunk ----
    vfloat4* __restrict__ o = (vfloat4*)out
        + (size_t)b * F4_PER_B + (size_t)x * F4_PER_BLOCK;
    const unsigned m0 = tid % 3u;

    #pragma unroll 1
    for (int c = 0; c < 8; ++c) {
        const float v3c = s_tab[24 + c];
        #pragma unroll
        for (int j = 0; j < 3; ++j) {
            const unsigned mj = (m0 + (unsigned)j) % 3u;  // c-invariant, hoisted
            vfloat4 val = pat4[j * 256 + tid];            // conflict-free b128
            val.w = (mj == 0u) ? v3c : val.w;             // group position 3
            val.y = (mj == 2u) ? v3c : val.y;             // group position 9
            o[c * PAT_F4 + j * 256 + tid] = val;
        }
    }
}

extern "C" void kernel_launch(void* const* d_in, const int* in_sizes, int n_in,
                              void* d_out, int out_size, void* d_ws, size_t ws_size,
                              hipStream_t stream) {
    const float* phi = (const float*)d_in[0];  // (32, 6)
    const float* rp  = (const float*)d_in[1];  // (6, 8, 1)
    const float* W1  = (const float*)d_in[2];  // (64, 2)
    const float* b1  = (const float*)d_in[3];  // (64,)
    const float* W2  = (const float*)d_in[4];  // (64, 64)
    const float* b2  = (const float*)d_in[5];  // (64,)
    const float* W3  = (const float*)d_in[6];  // (6, 64)
    const float* b3  = (const float*)d_in[7];  // (6,)
    float* out = (float*)d_out;
    float* q0  = (float*)d_ws;                 // 1536 floats = 6 KB

    q0_kernel<<<NB * NL * NR, 64, 0, stream>>>(phi, rp, W1, b1, W2, b2, W3, b3, q0);

    dim3 grid(BLOCKS_PER_B, NB);
    scatter_kernel<<<grid, 256, 0, stream>>>(q0, out);
}